// Round 10
// baseline (1780.677 us; speedup 1.0000x reference)
//
#include <hip/hip_runtime.h>
#include <hip/hip_bf16.h>

#define DI __device__ __forceinline__

// Problem constants (fixed by the reference)
// B=8, N=4096, N0=16384, C=64, HID=256, H=W=128 (HW=16384), M=h2*w2=256, SR=8

DI float wsum(float v){
#pragma unroll
  for (int o = 32; o; o >>= 1) v += __shfl_xor(v, o, 64);
  return v;
}
DI float wmax(float v){
#pragma unroll
  for (int o = 32; o; o >>= 1) v = fmaxf(v, __shfl_xor(v, o, 64));
  return v;
}
DI unsigned short f2b(float f){            // f32 -> bf16 bits, RNE
  unsigned u = __float_as_uint(f);
  u = (u + 0x7FFFu + ((u >> 16) & 1u)) >> 16;
  return (unsigned short)u;
}
DI float b2f(unsigned short s){ return __uint_as_float(((unsigned)s) << 16); }

// K1: pixel index + count scatter + sum-of-weights scatter
__global__ __launch_bounds__(256) void k_pix(const float* __restrict__ loc,
    const int* __restrict__ idx, const float* __restrict__ aw,
    int* __restrict__ pix, float* __restrict__ cnt, float* __restrict__ sw){
  int t = blockIdx.x * 256 + threadIdx.x;          // 0..B*N0-1
  int b = t >> 14;
  float lx = (fminf(fmaxf(loc[2*t  ], -1.f), 1.f) + 1.f) * 0.5f;
  float ly = (fminf(fmaxf(loc[2*t+1], -1.f), 1.f) + 1.f) * 0.5f;
  int xi = (int)rintf(lx * 127.f); xi = min(max(xi, 0), 127);
  int yi = (int)rintf(ly * 127.f); yi = min(max(yi, 0), 127);
  int p = yi * 128 + xi;
  pix[t] = p;
  atomicAdd(&cnt[(b << 14) + p], 1.f);
  atomicAdd(&sw[(b << 12) + idx[t]], aw[t]);
}

// K2: layernorm(x) -> xn ; q = xn @ q_w^T + q_b
__global__ __launch_bounds__(256) void k_lnq(const float* __restrict__ x,
    const float* __restrict__ n1w, const float* __restrict__ n1b,
    const float* __restrict__ qw, const float* __restrict__ qb,
    float* __restrict__ xn, float* __restrict__ q){
  __shared__ float wq[64*64];                      // [c][j], fp32, 16KB
  int tid = threadIdx.x;
  { int j = tid & 63, cp = tid >> 6;
    for (int cc = 0; cc < 16; ++cc){ int c = cp*16 + cc; wq[c*64 + j] = qw[j*64 + c]; } }
  __syncthreads();
  int lane = tid & 63, w = tid >> 6;
  for (int rr = 0; rr < 16; ++rr){
    int row = blockIdx.x * 64 + w * 16 + rr;
    float xv = x[row*64 + lane];
    float m = wsum(xv) * (1.f/64.f);
    float d = xv - m;
    float var = wsum(d*d) * (1.f/64.f);
    float xnv = d * rsqrtf(var + 1e-5f) * n1w[lane] + n1b[lane];
    xn[row*64 + lane] = xnv;
    float acc = qb[lane];
#pragma unroll
    for (int c = 0; c < 64; ++c) acc += __shfl(xnv, c, 64) * wq[c*64 + lane];
    q[row*64 + lane] = acc;
  }
}

// K3: scatter xn into s1 at pix (token2map numerator; conf channel is identically 0)
__global__ __launch_bounds__(256) void k_scat1(const float* __restrict__ xn,
    const int* __restrict__ idx, const int* __restrict__ pix, float* __restrict__ s1){
  int t = blockIdx.x * 4 + (threadIdx.x >> 6);
  int lane = threadIdx.x & 63;
  int b = t >> 14;
  int j = idx[t], p = pix[t];
  atomicAdd(&s1[(((b << 14) + p) << 6) + lane], xn[(((b << 12) + j) << 6) + lane]);
}

// K4: 8x8/stride-8 conv (as GEMM) on s1/cnt + sr_b, layernorm(srn), then kv GEMM.
// K and V are written DIRECTLY in the bf16 packed layouts k_attn consumes:
//   kpack[b][c*256 + (m&63)*4 + (m>>6)]   = K[m][c]   (m = kv index 0..255)
//   vpack[b][(m>>2)*256 + c*4 + (m&3)]    = V[m][c]
__global__ __launch_bounds__(256) void k_srkv(const float* __restrict__ s1,
    const float* __restrict__ cnt, const float* __restrict__ srw, const float* __restrict__ srb,
    const float* __restrict__ snw, const float* __restrict__ snb,
    const float* __restrict__ kvw, const float* __restrict__ kvb,
    unsigned short* __restrict__ kpack, unsigned short* __restrict__ vpack){
  __shared__ unsigned short wl[256*64];            // bf16 weight chunk [kk][oc], 32KB
  __shared__ float patch[8*256];                   // [b][kk], 8KB
  int tid = threadIdx.x;
  int oy = blockIdx.x >> 4, ox = blockIdx.x & 15;
  int oc = tid & 63, bg = tid >> 6;                // b0=bg, b1=bg+4
  float acc0 = 0.f, acc1 = 0.f;
  for (int ch = 0; ch < 16; ++ch){
    for (int u = 0; u < 64; ++u){
      int e = u*256 + tid;
      wl[e] = f2b(srw[ch*16384 + e]);
    }
    for (int u = 0; u < 8; ++u){
      int e = u*256 + tid;
      int bb = e >> 8, r = e & 255;
      int pi = ch*4 + (r >> 6), ic = r & 63;
      int gp = (oy*8 + (pi >> 3))*128 + ox*8 + (pi & 7);
      int pidx = (bb << 14) + gp;
      patch[bb*256 + r] = s1[(pidx << 6) + ic] * (1.f/(cnt[pidx] + 1e-6f));
    }
    __syncthreads();
#pragma unroll 8
    for (int kk = 0; kk < 256; ++kk){
      float wv = b2f(wl[kk*64 + oc]);
      acc0 += patch[bg*256 + kk] * wv;
      acc1 += patch[(bg+4)*256 + kk] * wv;
    }
    __syncthreads();
  }
  int om = blockIdx.x;                             // kv index m
  float t0 = acc0 + srb[oc];
  float t1 = acc1 + srb[oc];
  float m0 = wsum(t0) * (1.f/64.f), m1 = wsum(t1) * (1.f/64.f);
  float d0 = t0 - m0, d1 = t1 - m1;
  float v0 = wsum(d0*d0) * (1.f/64.f), v1 = wsum(d1*d1) * (1.f/64.f);
  float xr0 = d0 * rsqrtf(v0 + 1e-5f) * snw[oc] + snb[oc];
  float xr1 = d1 * rsqrtf(v1 + 1e-5f) * snw[oc] + snb[oc];
#pragma unroll
  for (int half = 0; half < 2; ++half){
    int j = half*64 + oc;
    float a0 = kvb[j], a1 = kvb[j];
#pragma unroll
    for (int c = 0; c < 64; ++c){
      float wv = kvw[j*64 + c];
      a0 += __shfl(xr0, c, 64) * wv;
      a1 += __shfl(xr1, c, 64) * wv;
    }
    if (half == 0){
      int off = oc*256 + (om & 63)*4 + (om >> 6);
      kpack[(bg    )*16384 + off] = f2b(a0);
      kpack[(bg + 4)*16384 + off] = f2b(a1);
    } else {
      int off = (om >> 2)*256 + oc*4 + (om & 3);
      vpack[(bg    )*16384 + off] = f2b(a0);
      vpack[(bg + 4)*16384 + off] = f2b(a1);
    }
  }
}

// K5: attention (HEADS=1, hd=64, M=256) + proj + residual -> x1
// No K/V LDS staging: packed bf16 K/V are streamed from global (L2-resident,
// 512B-contiguous per wave-read). LDS holds only proj_w (16KB, conflict-free).
// 1024 blocks x 4 waves; each wave computes 8 q-rows as 4 pairs (2-row ILP).
__global__ __launch_bounds__(256, 3) void k_attn(const float* __restrict__ x,
    const float* __restrict__ q, const unsigned short* __restrict__ kpack,
    const unsigned short* __restrict__ vpack,
    const float* __restrict__ pw, const float* __restrict__ pb, float* __restrict__ x1){
  __shared__ float pwl[64*64];                     // [c][j] : pw[j][c]
  int tid = threadIdx.x;
  for (int u = 0; u < 16; ++u){
    int e = u*256 + tid;
    pwl[e] = pw[(e & 63)*64 + (e >> 6)];
  }
  __syncthreads();
  int bi = blockIdx.x;
  int b  = bi >> 7;                                // 128 blocks per batch
  int lane = tid & 63, w = tid >> 6;
  const unsigned short* kp = kpack + b*16384;
  const unsigned short* vp = vpack + b*16384;
  float pbv = pb[lane];
  for (int pi = 0; pi < 4; ++pi){
    int row0 = (bi << 5) + (w << 3) + pi*2;
    int row1 = row0 + 1;
    float qv0 = q[row0*64 + lane], qv1 = q[row1*64 + lane];
    float s0[4] = {0.f,0.f,0.f,0.f}, s1v[4] = {0.f,0.f,0.f,0.f};
#pragma unroll
    for (int c = 0; c < 64; ++c){
      ushort4 k4 = *reinterpret_cast<const ushort4*>(kp + c*256 + lane*4);
      float qc0 = __shfl(qv0, c, 64);
      float qc1 = __shfl(qv1, c, 64);
      float k0 = b2f(k4.x), k1 = b2f(k4.y), k2 = b2f(k4.z), k3 = b2f(k4.w);
      s0[0] += qc0*k0; s0[1] += qc0*k1; s0[2] += qc0*k2; s0[3] += qc0*k3;
      s1v[0] += qc1*k0; s1v[1] += qc1*k1; s1v[2] += qc1*k2; s1v[3] += qc1*k3;
    }
#pragma unroll
    for (int t = 0; t < 4; ++t){ s0[t] *= 0.125f; s1v[t] *= 0.125f; }
    float mx0 = wmax(fmaxf(fmaxf(s0[0], s0[1]), fmaxf(s0[2], s0[3])));
    float mx1 = wmax(fmaxf(fmaxf(s1v[0], s1v[1]), fmaxf(s1v[2], s1v[3])));
    float e0[4], e1[4];
#pragma unroll
    for (int t = 0; t < 4; ++t){ e0[t] = __expf(s0[t]-mx0); e1[t] = __expf(s1v[t]-mx1); }
    float r0 = 1.f / wsum(e0[0]+e0[1]+e0[2]+e0[3]);
    float r1 = 1.f / wsum(e1[0]+e1[1]+e1[2]+e1[3]);
#pragma unroll
    for (int t = 0; t < 4; ++t){ e0[t] *= r0; e1[t] *= r1; }
    float a0 = 0.f, a1 = 0.f;
#pragma unroll
    for (int t = 0; t < 4; ++t){
#pragma unroll
      for (int gg = 0; gg < 16; ++gg){
        int g = t*16 + gg;
        ushort4 v4 = *reinterpret_cast<const ushort4*>(vp + g*256 + lane*4);
        float v0 = b2f(v4.x), v1 = b2f(v4.y), v2 = b2f(v4.z), v3 = b2f(v4.w);
        float w0a = __shfl(e0[t], gg*4+0, 64), w0b = __shfl(e0[t], gg*4+1, 64);
        float w0c = __shfl(e0[t], gg*4+2, 64), w0d = __shfl(e0[t], gg*4+3, 64);
        float w1a = __shfl(e1[t], gg*4+0, 64), w1b = __shfl(e1[t], gg*4+1, 64);
        float w1c = __shfl(e1[t], gg*4+2, 64), w1d = __shfl(e1[t], gg*4+3, 64);
        a0 += w0a*v0 + w0b*v1 + w0c*v2 + w0d*v3;
        a1 += w1a*v0 + w1b*v1 + w1c*v2 + w1d*v3;
      }
    }
    float pr0 = pbv, pr1 = pbv;
#pragma unroll
    for (int c = 0; c < 64; ++c){
      float wv = pwl[c*64 + lane];
      pr0 += __shfl(a0, c, 64) * wv;
      pr1 += __shfl(a1, c, 64) * wv;
    }
    x1[row0*64 + lane] = x[row0*64 + lane] + pr0;
    x1[row1*64 + lane] = x[row1*64 + lane] + pr1;
  }
}

// K6: h = layernorm(x1, n2) @ fc1_w^T + fc1_b   (out 256)
__global__ __launch_bounds__(256) void k_lnfc1(const float* __restrict__ x1,
    const float* __restrict__ n2w, const float* __restrict__ n2b,
    const float* __restrict__ w1, const float* __restrict__ b1, float* __restrict__ h){
  __shared__ unsigned short wlp[16384];   // [c][lane][t] bf16 : w1[t*64+lane][c], 32KB
  int tid = threadIdx.x;
  { int j = tid;
    for (int c = 0; c < 64; ++c)
      wlp[c*256 + (j & 63)*4 + (j >> 6)] = f2b(w1[j*64 + c]); }
  __syncthreads();
  int lane = tid & 63, w = tid >> 6;
  for (int rr = 0; rr < 16; ++rr){
    int row = blockIdx.x*64 + w*16 + rr;
    float xv = x1[row*64 + lane];
    float m = wsum(xv) * (1.f/64.f);
    float d = xv - m;
    float var = wsum(d*d) * (1.f/64.f);
    float xnv = d * rsqrtf(var + 1e-5f) * n2w[lane] + n2b[lane];
    float a0 = b1[lane], a1 = b1[64+lane], a2 = b1[128+lane], a3 = b1[192+lane];
#pragma unroll
    for (int c = 0; c < 64; ++c){
      ushort4 w4 = *reinterpret_cast<const ushort4*>(&wlp[c*256 + lane*4]);
      float xc = __shfl(xnv, c, 64);
      a0 += xc * b2f(w4.x); a1 += xc * b2f(w4.y);
      a2 += xc * b2f(w4.z); a3 += xc * b2f(w4.w);
    }
    int base = row*256 + lane;
    h[base] = a0; h[base+64] = a1; h[base+128] = a2; h[base+192] = a3;
  }
}

// K7: scatter h into hms at pix (token2map #2 numerator)
__global__ __launch_bounds__(256) void k_scat2(const float* __restrict__ h,
    const int* __restrict__ idx, const int* __restrict__ pix, float* __restrict__ hms){
  int t = blockIdx.x;
  int b = t >> 14;
  int j = idx[t], p = pix[t];
  int c = threadIdx.x;
  atomicAdd(&hms[((size_t)((b << 14) + p) << 8) + c], h[(((b << 12) + j) << 8) + c]);
}

// K8: fused (divide-by-count -> 3x3 depthwise conv -> gather at pix -> weighted scatter to tokens)
__global__ __launch_bounds__(256) void k_dwgather(const float* __restrict__ hms,
    const float* __restrict__ cnt, const float* __restrict__ dww, const float* __restrict__ dwb,
    const int* __restrict__ idx, const int* __restrict__ pix,
    const float* __restrict__ aw, const float* __restrict__ sw, float* __restrict__ h2){
  int t = blockIdx.x;
  int b = t >> 14;
  int j = idx[t], p = pix[t];
  int y = p >> 7, xx = p & 127;
  int c = threadIdx.x;
  float a = dwb[c];
#pragma unroll
  for (int dy = -1; dy <= 1; ++dy){
    int yy = y + dy; if (yy < 0 || yy > 127) continue;
#pragma unroll
    for (int dx = -1; dx <= 1; ++dx){
      int xp = xx + dx; if (xp < 0 || xp > 127) continue;
      int pp = (b << 14) + yy*128 + xp;
      float ic = 1.f/(cnt[pp] + 1e-6f);
      a += hms[((size_t)pp << 8) + c] * ic * dww[((dy+1)*3 + dx+1)*256 + c];
    }
  }
  float nw = aw[t] / (sw[(b << 12) + j] + 1e-6f);
  atomicAdd(&h2[(((b << 12) + j) << 8) + c], a * nw);
}

// K9: g = gelu(h2 + h*dwskip); out = x1 + g @ fc2_w^T + fc2_b
__global__ __launch_bounds__(256) void k_fc2(const float* __restrict__ h2,
    const float* __restrict__ h, const float* __restrict__ dskip,
    const float* __restrict__ w2, const float* __restrict__ b2,
    const float* __restrict__ x1, float* __restrict__ out){
  __shared__ unsigned short wlp[16384];   // [k>>2][c][k&3] bf16 : w2[c][k], 32KB
  int tid = threadIdx.x;
  { int c = tid & 63, kp = tid >> 6;
    for (int kk = 0; kk < 64; ++kk){
      int k = kp*64 + kk;
      wlp[(k >> 2)*256 + c*4 + (k & 3)] = f2b(w2[c*256 + k]);
    } }
  __syncthreads();
  int lane = tid & 63, w = tid >> 6;
  for (int rr = 0; rr < 16; ++rr){
    int row = blockIdx.x*64 + w*16 + rr;
    int base = row*256 + lane;
    float g[4];
#pragma unroll
    for (int tt = 0; tt < 4; ++tt){
      float hv = h2[base + 64*tt] + h[base + 64*tt] * dskip[lane + 64*tt];
      g[tt] = 0.5f * hv * (1.f + erff(hv * 0.70710678118654752f));
    }
    float acc = b2[lane];
#pragma unroll
    for (int t = 0; t < 4; ++t){
#pragma unroll
      for (int gg = 0; gg < 16; ++gg){
        int kg = t*16 + gg;
        ushort4 w4 = *reinterpret_cast<const ushort4*>(&wlp[(kg*64 + lane)*4]);
        acc += __shfl(g[t], gg*4+0, 64) * b2f(w4.x)
             + __shfl(g[t], gg*4+1, 64) * b2f(w4.y)
             + __shfl(g[t], gg*4+2, 64) * b2f(w4.z)
             + __shfl(g[t], gg*4+3, 64) * b2f(w4.w);
      }
    }
    out[row*64 + lane] = x1[row*64 + lane] + acc;
  }
}

extern "C" void kernel_launch(void* const* d_in, const int* in_sizes, int n_in,
                              void* d_out, int out_size, void* d_ws, size_t ws_size,
                              hipStream_t stream){
  const float* x    = (const float*)d_in[0];
  const float* loc  = (const float*)d_in[1];
  const int*   idx  = (const int*)d_in[2];
  const float* aw   = (const float*)d_in[3];
  const float* n1w  = (const float*)d_in[6];
  const float* n1b  = (const float*)d_in[7];
  const float* n2w  = (const float*)d_in[8];
  const float* n2b  = (const float*)d_in[9];
  const float* qw   = (const float*)d_in[10];
  const float* qb   = (const float*)d_in[11];
  const float* kvw  = (const float*)d_in[12];
  const float* kvb  = (const float*)d_in[13];
  const float* pw   = (const float*)d_in[14];
  const float* pb   = (const float*)d_in[15];
  const float* srw  = (const float*)d_in[16];
  const float* srb  = (const float*)d_in[17];
  const float* snw  = (const float*)d_in[18];
  const float* snb  = (const float*)d_in[19];
  const float* w1   = (const float*)d_in[20];
  const float* b1   = (const float*)d_in[21];
  const float* dww  = (const float*)d_in[22];
  const float* dwb  = (const float*)d_in[23];
  const float* dskp = (const float*)d_in[24];
  const float* w2   = (const float*)d_in[25];
  const float* b2   = (const float*)d_in[26];
  float* out = (float*)d_out;

  float* ws = (float*)d_ws;
  // layout (floats); hms region is lifetime-overlapped with s1/xn/q/kpack/vpack
  int*   pix = (int*)ws;                  // 131072
  float* cnt = ws + 131072;               // 131072
  float* sw  = ws + 262144;               // 32768
  float* x1  = ws + 294912;               // 2097152
  float* h   = ws + 2392064;              // 8388608
  float* h2  = ws + 10780672;             // 8388608
  float* hms = ws + 19169280;             // 33554432 (ends 52723712 floats ~211MB)
  float* s1  = hms;                       // 8388608  (dead after K4)
  float* xn  = hms + 8388608;             // 2097152  (dead after K3)
  float* q   = hms + 10485760;            // 2097152  (dead after K5)
  unsigned short* kpack = (unsigned short*)(hms + 12582912); // 131072 ushorts (dead after K5)
  unsigned short* vpack = kpack + 131072;                    // 131072 ushorts (dead after K5)

  // zero: cnt+sw, s1, h2
  hipMemsetAsync(cnt, 0, (size_t)(131072 + 32768) * 4, stream);
  hipMemsetAsync(s1,  0, (size_t)8388608 * 4, stream);
  hipMemsetAsync(h2,  0, (size_t)8388608 * 4, stream);

  k_pix   <<<512,    256, 0, stream>>>(loc, idx, aw, pix, cnt, sw);
  k_lnq   <<<512,    256, 0, stream>>>(x, n1w, n1b, qw, qb, xn, q);
  k_scat1 <<<32768,  256, 0, stream>>>(xn, idx, pix, s1);
  k_srkv  <<<256,    256, 0, stream>>>(s1, cnt, srw, srb, snw, snb, kvw, kvb, kpack, vpack);
  k_attn  <<<1024,   256, 0, stream>>>(x, q, kpack, vpack, pw, pb, x1);
  k_lnfc1 <<<512,    256, 0, stream>>>(x1, n2w, n2b, w1, b1, h);

  // hms region now free of live data -> zero it for scatter #2
  hipMemsetAsync(hms, 0, (size_t)33554432 * 4, stream);

  k_scat2    <<<131072, 256, 0, stream>>>(h, idx, pix, hms);
  k_dwgather <<<131072, 256, 0, stream>>>(hms, cnt, dww, dwb, idx, pix, aw, sw, h2);
  k_fc2      <<<512,    256, 0, stream>>>(h2, h, dskp, w2, b2, x1, out);
}

// Round 14
// 1372.478 us; speedup vs baseline: 1.2974x; 1.2974x over previous
//
#include <hip/hip_runtime.h>
#include <hip/hip_bf16.h>

#define DI __device__ __forceinline__

// Problem constants (fixed by the reference)
// B=8, N=4096, N0=16384, C=64, HID=256, H=W=128 (HW=16384), M=h2*w2=256, SR=8

DI float wsum(float v){
#pragma unroll
  for (int o = 32; o; o >>= 1) v += __shfl_xor(v, o, 64);
  return v;
}
DI float wmax(float v){
#pragma unroll
  for (int o = 32; o; o >>= 1) v = fmaxf(v, __shfl_xor(v, o, 64));
  return v;
}
DI unsigned short f2b(float f){            // f32 -> bf16 bits, RNE
  unsigned u = __float_as_uint(f);
  u = (u + 0x7FFFu + ((u >> 16) & 1u)) >> 16;
  return (unsigned short)u;
}
DI float b2f(unsigned short s){ return __uint_as_float(((unsigned)s) << 16); }

// K1: pixel index + count scatter + sum-of-weights scatter
__global__ __launch_bounds__(256) void k_pix(const float* __restrict__ loc,
    const int* __restrict__ idx, const float* __restrict__ aw,
    int* __restrict__ pix, float* __restrict__ cnt, float* __restrict__ sw){
  int t = blockIdx.x * 256 + threadIdx.x;          // 0..B*N0-1
  int b = t >> 14;
  float lx = (fminf(fmaxf(loc[2*t  ], -1.f), 1.f) + 1.f) * 0.5f;
  float ly = (fminf(fmaxf(loc[2*t+1], -1.f), 1.f) + 1.f) * 0.5f;
  int xi = (int)rintf(lx * 127.f); xi = min(max(xi, 0), 127);
  int yi = (int)rintf(ly * 127.f); yi = min(max(yi, 0), 127);
  int p = yi * 128 + xi;
  pix[t] = p;
  atomicAdd(&cnt[(b << 14) + p], 1.f);
  atomicAdd(&sw[(b << 12) + idx[t]], aw[t]);
}

// K2: layernorm(x) -> xn ; q = xn @ q_w^T + q_b
__global__ __launch_bounds__(256) void k_lnq(const float* __restrict__ x,
    const float* __restrict__ n1w, const float* __restrict__ n1b,
    const float* __restrict__ qw, const float* __restrict__ qb,
    float* __restrict__ xn, float* __restrict__ q){
  __shared__ float wq[64*64];                      // [c][j], fp32, 16KB
  int tid = threadIdx.x;
  { int j = tid & 63, cp = tid >> 6;
    for (int cc = 0; cc < 16; ++cc){ int c = cp*16 + cc; wq[c*64 + j] = qw[j*64 + c]; } }
  __syncthreads();
  int lane = tid & 63, w = tid >> 6;
  for (int rr = 0; rr < 16; ++rr){
    int row = blockIdx.x * 64 + w * 16 + rr;
    float xv = x[row*64 + lane];
    float m = wsum(xv) * (1.f/64.f);
    float d = xv - m;
    float var = wsum(d*d) * (1.f/64.f);
    float xnv = d * rsqrtf(var + 1e-5f) * n1w[lane] + n1b[lane];
    xn[row*64 + lane] = xnv;
    float acc = qb[lane];
#pragma unroll
    for (int c = 0; c < 64; ++c) acc += __shfl(xnv, c, 64) * wq[c*64 + lane];
    q[row*64 + lane] = acc;
  }
}

// K3: scatter xn into s1 at pix (token2map numerator; conf channel is identically 0)
__global__ __launch_bounds__(256) void k_scat1(const float* __restrict__ xn,
    const int* __restrict__ idx, const int* __restrict__ pix, float* __restrict__ s1){
  int t = blockIdx.x * 4 + (threadIdx.x >> 6);
  int lane = threadIdx.x & 63;
  int b = t >> 14;
  int j = idx[t], p = pix[t];
  atomicAdd(&s1[(((b << 14) + p) << 6) + lane], xn[(((b << 12) + j) << 6) + lane]);
}

// K4: 8x8/stride-8 conv (as GEMM) on s1/cnt + sr_b, layernorm(srn), then kv GEMM.
// K and V are written DIRECTLY in the bf16 packed layouts k_attn consumes:
//   kpack[b][c*256 + (m&63)*4 + (m>>6)]   = K[m][c]   (m = kv index 0..255)
//   vpack[b][(m>>2)*256 + c*4 + (m&3)]    = V[m][c]
__global__ __launch_bounds__(256) void k_srkv(const float* __restrict__ s1,
    const float* __restrict__ cnt, const float* __restrict__ srw, const float* __restrict__ srb,
    const float* __restrict__ snw, const float* __restrict__ snb,
    const float* __restrict__ kvw, const float* __restrict__ kvb,
    unsigned short* __restrict__ kpack, unsigned short* __restrict__ vpack){
  __shared__ unsigned short wl[256*64];            // bf16 weight chunk [kk][oc], 32KB
  __shared__ float patch[8*256];                   // [b][kk], 8KB
  int tid = threadIdx.x;
  int oy = blockIdx.x >> 4, ox = blockIdx.x & 15;
  int oc = tid & 63, bg = tid >> 6;                // b0=bg, b1=bg+4
  float acc0 = 0.f, acc1 = 0.f;
  for (int ch = 0; ch < 16; ++ch){
    for (int u = 0; u < 64; ++u){
      int e = u*256 + tid;
      wl[e] = f2b(srw[ch*16384 + e]);
    }
    for (int u = 0; u < 8; ++u){
      int e = u*256 + tid;
      int bb = e >> 8, r = e & 255;
      int pi = ch*4 + (r >> 6), ic = r & 63;
      int gp = (oy*8 + (pi >> 3))*128 + ox*8 + (pi & 7);
      int pidx = (bb << 14) + gp;
      patch[bb*256 + r] = s1[(pidx << 6) + ic] * (1.f/(cnt[pidx] + 1e-6f));
    }
    __syncthreads();
#pragma unroll 8
    for (int kk = 0; kk < 256; ++kk){
      float wv = b2f(wl[kk*64 + oc]);
      acc0 += patch[bg*256 + kk] * wv;
      acc1 += patch[(bg+4)*256 + kk] * wv;
    }
    __syncthreads();
  }
  int om = blockIdx.x;                             // kv index m
  float t0 = acc0 + srb[oc];
  float t1 = acc1 + srb[oc];
  float m0 = wsum(t0) * (1.f/64.f), m1 = wsum(t1) * (1.f/64.f);
  float d0 = t0 - m0, d1 = t1 - m1;
  float v0 = wsum(d0*d0) * (1.f/64.f), v1 = wsum(d1*d1) * (1.f/64.f);
  float xr0 = d0 * rsqrtf(v0 + 1e-5f) * snw[oc] + snb[oc];
  float xr1 = d1 * rsqrtf(v1 + 1e-5f) * snw[oc] + snb[oc];
#pragma unroll
  for (int half = 0; half < 2; ++half){
    int j = half*64 + oc;
    float a0 = kvb[j], a1 = kvb[j];
#pragma unroll
    for (int c = 0; c < 64; ++c){
      float wv = kvw[j*64 + c];
      a0 += __shfl(xr0, c, 64) * wv;
      a1 += __shfl(xr1, c, 64) * wv;
    }
    if (half == 0){
      int off = oc*256 + (om & 63)*4 + (om >> 6);
      kpack[(bg    )*16384 + off] = f2b(a0);
      kpack[(bg + 4)*16384 + off] = f2b(a1);
    } else {
      int off = (om >> 2)*256 + oc*4 + (om & 3);
      vpack[(bg    )*16384 + off] = f2b(a0);
      vpack[(bg + 4)*16384 + off] = f2b(a1);
    }
  }
}

// K5: attention (HEADS=1, hd=64, M=256) + proj + residual -> x1
// LDS-staged packed bf16 K/V (coalesced 16B copies from kpack/vpack),
// 512-thread blocks, 80KB LDS -> 2 blocks/CU = 4 waves/SIMD (2x round-8 occ).
// Each wave computes 8 q-rows as 4 pairs (2-row ILP).
__global__ __launch_bounds__(512, 4) void k_attn(const float* __restrict__ x,
    const float* __restrict__ q, const unsigned short* __restrict__ kpack,
    const unsigned short* __restrict__ vpack,
    const float* __restrict__ pw, const float* __restrict__ pb, float* __restrict__ x1){
  __shared__ unsigned short klp[16384];   // 32KB, same layout as kpack[b]
  __shared__ unsigned short vlp[16384];   // 32KB, same layout as vpack[b]
  __shared__ float pwl[64*64];            // [c][j] : pw[j][c], 16KB
  int tid = threadIdx.x;
  int bi = blockIdx.x;
  int b  = bi >> 6;                                // 64 blocks per batch
  { // coalesced 16B staging copies
    const uint4* kg = reinterpret_cast<const uint4*>(kpack + (size_t)b*16384);
    const uint4* vg = reinterpret_cast<const uint4*>(vpack + (size_t)b*16384);
    uint4* kl = reinterpret_cast<uint4*>(klp);
    uint4* vl = reinterpret_cast<uint4*>(vlp);
#pragma unroll
    for (int u = 0; u < 4; ++u){
      int e = u*512 + tid;                         // 2048 uint4 per buffer
      kl[e] = kg[e];
      vl[e] = vg[e];
    }
    for (int u = 0; u < 8; ++u){
      int e = u*512 + tid;
      pwl[e] = pw[(e & 63)*64 + (e >> 6)];
    }
  }
  __syncthreads();
  int lane = tid & 63, w = tid >> 6;               // w in [0,8)
  float pbv = pb[lane];
  for (int pi = 0; pi < 4; ++pi){
    int row0 = (bi << 6) + (w << 3) + pi*2;
    int row1 = row0 + 1;
    float qv0 = q[row0*64 + lane], qv1 = q[row1*64 + lane];
    float s0[4] = {0.f,0.f,0.f,0.f}, s1v[4] = {0.f,0.f,0.f,0.f};
#pragma unroll
    for (int c = 0; c < 64; ++c){
      ushort4 k4 = *reinterpret_cast<const ushort4*>(&klp[c*256 + lane*4]);
      float qc0 = __shfl(qv0, c, 64);
      float qc1 = __shfl(qv1, c, 64);
      float k0 = b2f(k4.x), k1 = b2f(k4.y), k2 = b2f(k4.z), k3 = b2f(k4.w);
      s0[0] += qc0*k0; s0[1] += qc0*k1; s0[2] += qc0*k2; s0[3] += qc0*k3;
      s1v[0] += qc1*k0; s1v[1] += qc1*k1; s1v[2] += qc1*k2; s1v[3] += qc1*k3;
    }
#pragma unroll
    for (int t = 0; t < 4; ++t){ s0[t] *= 0.125f; s1v[t] *= 0.125f; }
    float mx0 = wmax(fmaxf(fmaxf(s0[0], s0[1]), fmaxf(s0[2], s0[3])));
    float mx1 = wmax(fmaxf(fmaxf(s1v[0], s1v[1]), fmaxf(s1v[2], s1v[3])));
    float e0[4], e1[4];
#pragma unroll
    for (int t = 0; t < 4; ++t){ e0[t] = __expf(s0[t]-mx0); e1[t] = __expf(s1v[t]-mx1); }
    float r0 = 1.f / wsum(e0[0]+e0[1]+e0[2]+e0[3]);
    float r1 = 1.f / wsum(e1[0]+e1[1]+e1[2]+e1[3]);
#pragma unroll
    for (int t = 0; t < 4; ++t){ e0[t] *= r0; e1[t] *= r1; }
    float a0 = 0.f, a1 = 0.f;
#pragma unroll
    for (int t = 0; t < 4; ++t){
#pragma unroll
      for (int gg = 0; gg < 16; ++gg){
        int g = t*16 + gg;
        ushort4 v4 = *reinterpret_cast<const ushort4*>(&vlp[g*256 + lane*4]);
        float v0 = b2f(v4.x), v1 = b2f(v4.y), v2 = b2f(v4.z), v3 = b2f(v4.w);
        float w0a = __shfl(e0[t], gg*4+0, 64), w0b = __shfl(e0[t], gg*4+1, 64);
        float w0c = __shfl(e0[t], gg*4+2, 64), w0d = __shfl(e0[t], gg*4+3, 64);
        float w1a = __shfl(e1[t], gg*4+0, 64), w1b = __shfl(e1[t], gg*4+1, 64);
        float w1c = __shfl(e1[t], gg*4+2, 64), w1d = __shfl(e1[t], gg*4+3, 64);
        a0 += w0a*v0 + w0b*v1 + w0c*v2 + w0d*v3;
        a1 += w1a*v0 + w1b*v1 + w1c*v2 + w1d*v3;
      }
    }
    float pr0 = pbv, pr1 = pbv;
#pragma unroll
    for (int c = 0; c < 64; ++c){
      float wv = pwl[c*64 + lane];
      pr0 += __shfl(a0, c, 64) * wv;
      pr1 += __shfl(a1, c, 64) * wv;
    }
    x1[row0*64 + lane] = x[row0*64 + lane] + pr0;
    x1[row1*64 + lane] = x[row1*64 + lane] + pr1;
  }
}

// K6: h = layernorm(x1, n2) @ fc1_w^T + fc1_b   (out 256)
__global__ __launch_bounds__(256) void k_lnfc1(const float* __restrict__ x1,
    const float* __restrict__ n2w, const float* __restrict__ n2b,
    const float* __restrict__ w1, const float* __restrict__ b1, float* __restrict__ h){
  __shared__ unsigned short wlp[16384];   // [c][lane][t] bf16 : w1[t*64+lane][c], 32KB
  int tid = threadIdx.x;
  { int j = tid;
    for (int c = 0; c < 64; ++c)
      wlp[c*256 + (j & 63)*4 + (j >> 6)] = f2b(w1[j*64 + c]); }
  __syncthreads();
  int lane = tid & 63, w = tid >> 6;
  for (int rr = 0; rr < 16; ++rr){
    int row = blockIdx.x*64 + w*16 + rr;
    float xv = x1[row*64 + lane];
    float m = wsum(xv) * (1.f/64.f);
    float d = xv - m;
    float var = wsum(d*d) * (1.f/64.f);
    float xnv = d * rsqrtf(var + 1e-5f) * n2w[lane] + n2b[lane];
    float a0 = b1[lane], a1 = b1[64+lane], a2 = b1[128+lane], a3 = b1[192+lane];
#pragma unroll
    for (int c = 0; c < 64; ++c){
      ushort4 w4 = *reinterpret_cast<const ushort4*>(&wlp[c*256 + lane*4]);
      float xc = __shfl(xnv, c, 64);
      a0 += xc * b2f(w4.x); a1 += xc * b2f(w4.y);
      a2 += xc * b2f(w4.z); a3 += xc * b2f(w4.w);
    }
    int base = row*256 + lane;
    h[base] = a0; h[base+64] = a1; h[base+128] = a2; h[base+192] = a3;
  }
}

// K7: scatter h into hms at pix (token2map #2 numerator)
__global__ __launch_bounds__(256) void k_scat2(const float* __restrict__ h,
    const int* __restrict__ idx, const int* __restrict__ pix, float* __restrict__ hms){
  int t = blockIdx.x;
  int b = t >> 14;
  int j = idx[t], p = pix[t];
  int c = threadIdx.x;
  atomicAdd(&hms[((size_t)((b << 14) + p) << 8) + c], h[(((b << 12) + j) << 8) + c]);
}

// K8: fused (divide-by-count -> 3x3 depthwise conv -> gather at pix -> weighted scatter to tokens)
__global__ __launch_bounds__(256) void k_dwgather(const float* __restrict__ hms,
    const float* __restrict__ cnt, const float* __restrict__ dww, const float* __restrict__ dwb,
    const int* __restrict__ idx, const int* __restrict__ pix,
    const float* __restrict__ aw, const float* __restrict__ sw, float* __restrict__ h2){
  int t = blockIdx.x;
  int b = t >> 14;
  int j = idx[t], p = pix[t];
  int y = p >> 7, xx = p & 127;
  int c = threadIdx.x;
  float a = dwb[c];
#pragma unroll
  for (int dy = -1; dy <= 1; ++dy){
    int yy = y + dy; if (yy < 0 || yy > 127) continue;
#pragma unroll
    for (int dx = -1; dx <= 1; ++dx){
      int xp = xx + dx; if (xp < 0 || xp > 127) continue;
      int pp = (b << 14) + yy*128 + xp;
      float ic = 1.f/(cnt[pp] + 1e-6f);
      a += hms[((size_t)pp << 8) + c] * ic * dww[((dy+1)*3 + dx+1)*256 + c];
    }
  }
  float nw = aw[t] / (sw[(b << 12) + j] + 1e-6f);
  atomicAdd(&h2[(((b << 12) + j) << 8) + c], a * nw);
}

// K9: g = gelu(h2 + h*dwskip); out = x1 + g @ fc2_w^T + fc2_b
__global__ __launch_bounds__(256) void k_fc2(const float* __restrict__ h2,
    const float* __restrict__ h, const float* __restrict__ dskip,
    const float* __restrict__ w2, const float* __restrict__ b2,
    const float* __restrict__ x1, float* __restrict__ out){
  __shared__ unsigned short wlp[16384];   // [k>>2][c][k&3] bf16 : w2[c][k], 32KB
  int tid = threadIdx.x;
  { int c = tid & 63, kp = tid >> 6;
    for (int kk = 0; kk < 64; ++kk){
      int k = kp*64 + kk;
      wlp[(k >> 2)*256 + c*4 + (k & 3)] = f2b(w2[c*256 + k]);
    } }
  __syncthreads();
  int lane = tid & 63, w = tid >> 6;
  for (int rr = 0; rr < 16; ++rr){
    int row = blockIdx.x*64 + w*16 + rr;
    int base = row*256 + lane;
    float g[4];
#pragma unroll
    for (int tt = 0; tt < 4; ++tt){
      float hv = h2[base + 64*tt] + h[base + 64*tt] * dskip[lane + 64*tt];
      g[tt] = 0.5f * hv * (1.f + erff(hv * 0.70710678118654752f));
    }
    float acc = b2[lane];
#pragma unroll
    for (int t = 0; t < 4; ++t){
#pragma unroll
      for (int gg = 0; gg < 16; ++gg){
        int kg = t*16 + gg;
        ushort4 w4 = *reinterpret_cast<const ushort4*>(&wlp[(kg*64 + lane)*4]);
        acc += __shfl(g[t], gg*4+0, 64) * b2f(w4.x)
             + __shfl(g[t], gg*4+1, 64) * b2f(w4.y)
             + __shfl(g[t], gg*4+2, 64) * b2f(w4.z)
             + __shfl(g[t], gg*4+3, 64) * b2f(w4.w);
      }
    }
    out[row*64 + lane] = x1[row*64 + lane] + acc;
  }
}

extern "C" void kernel_launch(void* const* d_in, const int* in_sizes, int n_in,
                              void* d_out, int out_size, void* d_ws, size_t ws_size,
                              hipStream_t stream){
  const float* x    = (const float*)d_in[0];
  const float* loc  = (const float*)d_in[1];
  const int*   idx  = (const int*)d_in[2];
  const float* aw   = (const float*)d_in[3];
  const float* n1w  = (const float*)d_in[6];
  const float* n1b  = (const float*)d_in[7];
  const float* n2w  = (const float*)d_in[8];
  const float* n2b  = (const float*)d_in[9];
  const float* qw   = (const float*)d_in[10];
  const float* qb   = (const float*)d_in[11];
  const float* kvw  = (const float*)d_in[12];
  const float* kvb  = (const float*)d_in[13];
  const float* pw   = (const float*)d_in[14];
  const float* pb   = (const float*)d_in[15];
  const float* srw  = (const float*)d_in[16];
  const float* srb  = (const float*)d_in[17];
  const float* snw  = (const float*)d_in[18];
  const float* snb  = (const float*)d_in[19];
  const float* w1   = (const float*)d_in[20];
  const float* b1   = (const float*)d_in[21];
  const float* dww  = (const float*)d_in[22];
  const float* dwb  = (const float*)d_in[23];
  const float* dskp = (const float*)d_in[24];
  const float* w2   = (const float*)d_in[25];
  const float* b2   = (const float*)d_in[26];
  float* out = (float*)d_out;

  float* ws = (float*)d_ws;
  // layout (floats); hms region is lifetime-overlapped with s1/xn/q/kpack/vpack
  int*   pix = (int*)ws;                  // 131072
  float* cnt = ws + 131072;               // 131072
  float* sw  = ws + 262144;               // 32768
  float* x1  = ws + 294912;               // 2097152
  float* h   = ws + 2392064;              // 8388608
  float* h2  = ws + 10780672;             // 8388608
  float* hms = ws + 19169280;             // 33554432 (ends 52723712 floats ~211MB)
  float* s1  = hms;                       // 8388608  (dead after K4)
  float* xn  = hms + 8388608;             // 2097152  (dead after K3)
  float* q   = hms + 10485760;            // 2097152  (dead after K5)
  unsigned short* kpack = (unsigned short*)(hms + 12582912); // 131072 ushorts (dead after K5)
  unsigned short* vpack = kpack + 131072;                    // 131072 ushorts (dead after K5)

  // zero: cnt+sw, s1, h2
  hipMemsetAsync(cnt, 0, (size_t)(131072 + 32768) * 4, stream);
  hipMemsetAsync(s1,  0, (size_t)8388608 * 4, stream);
  hipMemsetAsync(h2,  0, (size_t)8388608 * 4, stream);

  k_pix   <<<512,    256, 0, stream>>>(loc, idx, aw, pix, cnt, sw);
  k_lnq   <<<512,    256, 0, stream>>>(x, n1w, n1b, qw, qb, xn, q);
  k_scat1 <<<32768,  256, 0, stream>>>(xn, idx, pix, s1);
  k_srkv  <<<256,    256, 0, stream>>>(s1, cnt, srw, srb, snw, snb, kvw, kvb, kpack, vpack);
  k_attn  <<<512,    512, 0, stream>>>(x, q, kpack, vpack, pw, pb, x1);
  k_lnfc1 <<<512,    256, 0, stream>>>(x1, n2w, n2b, w1, b1, h);

  // hms region now free of live data -> zero it for scatter #2
  hipMemsetAsync(hms, 0, (size_t)33554432 * 4, stream);

  k_scat2    <<<131072, 256, 0, stream>>>(h, idx, pix, hms);
  k_dwgather <<<131072, 256, 0, stream>>>(hms, cnt, dww, dwb, idx, pix, aw, sw, h2);
  k_fc2      <<<512,    256, 0, stream>>>(h2, h, dskp, w2, b2, x1, out);
}